// Round 3
// baseline (1074.431 us; speedup 1.0000x reference)
//
#include <hip/hip_runtime.h>
#include <math.h>

// Problem constants (B=1)
#define NRES 768
#define DIMM 384
#define NH   12

#define SCALAR_SCALE 0.14433756729740646f   // (3*16)^-0.5
#define HALF_POINT   0.06804138174397717f   // 0.5 * (3*4*4.5)^-0.5
#define PAIR_SCALE   0.5773502691896258f    // 3^-0.5

// -------------------- K1: projections + to_global --------------------
// grid 384 x 256 thr; block = 2 residue rows (more blocks -> latency spread).
__global__ __launch_bounds__(256) void k1_proj(
    const float* __restrict__ x, const float* __restrict__ rot, const float* __restrict__ trans,
    const float* __restrict__ Wqs, const float* __restrict__ Wks, const float* __restrict__ Wvs,
    const float* __restrict__ Wqp, const float* __restrict__ Wkp, const float* __restrict__ Wvp,
    float* __restrict__ qs, float* __restrict__ ks, float* __restrict__ vs,
    float* __restrict__ qpg, float* __restrict__ kpg, float* __restrict__ vpg)
{
    __shared__ float xs[2 * 384];
    __shared__ float xp[3][2][144];

    const int tid = threadIdx.x;
    const int n0 = blockIdx.x * 2;

    for (int idx = tid; idx < 192; idx += 256)
        ((float4*)xs)[idx] = ((const float4*)(x + (size_t)n0 * 384))[idx];
    __syncthreads();

    if (tid < 252) {
        const int g = tid;
        int m, c0, wd;
        if (g < 144) { m = g / 48; c0 = (g - m * 48) * 4; wd = 192; }
        else { int z = g - 144; m = 3 + z / 36; c0 = (z - (m - 3) * 36) * 4; wd = 144; }
        const float* Wm = (m==0)?Wqs : (m==1)?Wks : (m==2)?Wvs : (m==3)?Wqp : (m==4)?Wkp : Wvp;
        const float* wp = Wm + c0;
        float acc[2][4] = {};
        #pragma unroll 4
        for (int k = 0; k < DIMM; ++k) {
            float4 w = *(const float4*)wp; wp += wd;
            #pragma unroll
            for (int r = 0; r < 2; ++r) {
                float xv = xs[r * 384 + k];
                acc[r][0] = fmaf(xv, w.x, acc[r][0]);
                acc[r][1] = fmaf(xv, w.y, acc[r][1]);
                acc[r][2] = fmaf(xv, w.z, acc[r][2]);
                acc[r][3] = fmaf(xv, w.w, acc[r][3]);
            }
        }
        if (m < 3) {
            float* dst = (m==0)?qs : (m==1)?ks : vs;
            #pragma unroll
            for (int r = 0; r < 2; ++r) {
                float4 st = make_float4(acc[r][0], acc[r][1], acc[r][2], acc[r][3]);
                *(float4*)(dst + (size_t)(n0 + r) * 192 + c0) = st;
            }
        } else {
            int mi = m - 3;
            #pragma unroll
            for (int r = 0; r < 2; ++r)
                #pragma unroll
                for (int u = 0; u < 4; ++u) xp[mi][r][c0 + u] = acc[r][u];
        }
    }
    __syncthreads();

    for (int t = tid; t < 288; t += 256) {
        int mi = t / 96; int rm = t - mi * 96; int r = rm / 48; int pt = rm - r * 48; int c0 = pt * 3;
        float p0 = xp[mi][r][c0+0], p1 = xp[mi][r][c0+1], p2 = xp[mi][r][c0+2];
        int n = n0 + r;
        const float* R = rot + n * 9; const float* T = trans + n * 3;
        float g0 = fmaf(R[0], p0, fmaf(R[1], p1, fmaf(R[2], p2, T[0])));
        float g1 = fmaf(R[3], p0, fmaf(R[4], p1, fmaf(R[5], p2, T[1])));
        float g2 = fmaf(R[6], p0, fmaf(R[7], p1, fmaf(R[8], p2, T[2])));
        float* dst = (mi==0)?qpg : (mi==1)?kpg : vpg;
        dst[n*144 + c0+0] = g0; dst[n*144 + c0+1] = g1; dst[n*144 + c0+2] = g2;
    }
}

// -------------------- K2: single-pass fused attention (online softmax) -----
// One block per query row i; 12 j-tiles of 64. Register-prefetch double
// buffering of the pairwise tile; 3 barriers/tile; LDS 38 KB -> 4 blocks/CU.
__global__ __launch_bounds__(256, 4) void k2_attn(
    const float* __restrict__ pairwise, const float* __restrict__ rot, const float* __restrict__ trans,
    const float* __restrict__ Wp, const float* __restrict__ bp, const float* __restrict__ ptw,
    const float* __restrict__ qs, const float* __restrict__ ks, const float* __restrict__ vs,
    const float* __restrict__ qpg, const float* __restrict__ kpg, const float* __restrict__ vpg,
    float* __restrict__ results)
{
    __shared__ float Pt[64 * 129];        // pairwise tile (padded: 2-way max)
    __shared__ float E[64 * 14];          // unnormalized exp [j][h], even stride
    __shared__ float Qs[192], Qp[144];
    __shared__ float mL[12], lL[12], aL[12], invL[12], hpL[12], bpL[12];
    __shared__ float rp_l[144];

    const int tid = threadIdx.x;
    const int i = blockIdx.x;
    const size_t ri = (size_t)i * 1920;

    if (tid < 48)               ((float4*)Qs)[tid]      = ((const float4*)(qs  + (size_t)i * 192))[tid];
    if (tid >= 64 && tid < 100) ((float4*)Qp)[tid - 64] = ((const float4*)(qpg + (size_t)i * 144))[tid - 64];
    if (tid >= 128 && tid < 140) {
        int h = tid - 128;
        hpL[h] = HALF_POINT * log1pf(__expf(ptw[h]));
        bpL[h] = PAIR_SCALE * bp[h];
        mL[h] = -3.0e38f; lL[h] = 0.f;
    }

    const int j  = tid & 63;
    const int hg = __builtin_amdgcn_readfirstlane(tid >> 6);  // wave head-group (scalar)
    const int hh = tid >> 7, dpr = tid & 127, hb = hh * 6;    // r_pair mapping
    const int hs = tid >> 4;          // r_scalar head (tid<192)
    const int hq = tid / 12;          // r_point head  (tid<144)

    // prefetch tile 0 into registers
    const float4* Pg = (const float4*)(pairwise + (size_t)i * NRES * 128);
    float4 pf[8];
    #pragma unroll
    for (int q = 0; q < 8; ++q) pf[q] = Pg[tid + 256 * q];

    float accp[6] = {0.f,0.f,0.f,0.f,0.f,0.f};
    float accs = 0.f, accq = 0.f;

    for (int tile = 0; tile < 12; ++tile) {
        // ---- commit prefetched tile to LDS, then issue next prefetch ----
        #pragma unroll
        for (int q = 0; q < 8; ++q) {
            int idx = tid + 256 * q;
            int row = idx >> 5, c4 = (idx & 31) << 2;
            float* dp = &Pt[row * 129 + c4];
            dp[0] = pf[q].x; dp[1] = pf[q].y; dp[2] = pf[q].z; dp[3] = pf[q].w;
        }
        if (tile < 11) {
            const float4* Pn = Pg + (size_t)(tile + 1) * 2048;
            #pragma unroll
            for (int q = 0; q < 8; ++q) pf[q] = Pn[tid + 256 * q];
        }
        __syncthreads();   // Pt ready (also covers Qs/consts on tile 0)

        // ---- Phase BC: logits (qk + points + full-dot pair bias) + softmax ----
        {
            const int jg = tile * 64 + j;
            const float* kr  = ks  + (size_t)jg * 192;
            const float* kpr = kpg + (size_t)jg * 144;
            float own[3];
            #pragma unroll
            for (int e = 0; e < 3; ++e) {
                int h = 3 * hg + e;
                const float4* kv = (const float4*)(kr + h * 16);
                float4 a0 = kv[0], a1 = kv[1], a2 = kv[2], a3 = kv[3];
                const float4* qv = (const float4*)(Qs + h * 16);
                float4 q0 = qv[0], q1 = qv[1], q2 = qv[2], q3 = qv[3];
                float s = q0.x*a0.x + q0.y*a0.y + q0.z*a0.z + q0.w*a0.w
                        + q1.x*a1.x + q1.y*a1.y + q1.z*a1.z + q1.w*a1.w
                        + q2.x*a2.x + q2.y*a2.y + q2.z*a2.z + q2.w*a2.w
                        + q3.x*a3.x + q3.y*a3.y + q3.z*a3.z + q3.w*a3.w;
                const float4* pv = (const float4*)(kpr + h * 12);
                float4 p0 = pv[0], p1 = pv[1], p2 = pv[2];
                const float4* qpv = (const float4*)(Qp + h * 12);
                float4 u0 = qpv[0], u1 = qpv[1], u2 = qpv[2];
                float dv, dist;
                dv = u0.x - p0.x; dist  = dv*dv;
                dv = u0.y - p0.y; dist += dv*dv;
                dv = u0.z - p0.z; dist += dv*dv;
                dv = u0.w - p0.w; dist += dv*dv;
                dv = u1.x - p1.x; dist += dv*dv;
                dv = u1.y - p1.y; dist += dv*dv;
                dv = u1.z - p1.z; dist += dv*dv;
                dv = u1.w - p1.w; dist += dv*dv;
                dv = u2.x - p2.x; dist += dv*dv;
                dv = u2.y - p2.y; dist += dv*dv;
                dv = u2.z - p2.z; dist += dv*dv;
                dv = u2.w - p2.w; dist += dv*dv;
                own[e] = SCALAR_SCALE * s - hpL[h] * dist + bpL[h];
            }
            // pair bias: full 128-dot, 3 heads; Wp via wave-uniform s_loads (K$)
            float pb0 = 0.f, pb1 = 0.f, pb2 = 0.f;
            const float* Prow = &Pt[j * 129];
            const float* Wh = Wp + 3 * hg;
            #pragma unroll 8
            for (int d = 0; d < 128; ++d) {
                float p = Prow[d];
                pb0 = fmaf(p, Wh[d * 12 + 0], pb0);
                pb1 = fmaf(p, Wh[d * 12 + 1], pb1);
                pb2 = fmaf(p, Wh[d * 12 + 2], pb2);
            }
            float Lv[3], tm[3];
            Lv[0] = own[0] + PAIR_SCALE * pb0;
            Lv[1] = own[1] + PAIR_SCALE * pb1;
            Lv[2] = own[2] + PAIR_SCALE * pb2;
            #pragma unroll
            for (int e = 0; e < 3; ++e) tm[e] = Lv[e];
            #pragma unroll
            for (int o = 32; o > 0; o >>= 1) {
                #pragma unroll
                for (int e = 0; e < 3; ++e) tm[e] = fmaxf(tm[e], __shfl_xor(tm[e], o));
            }
            float ss[3], mnv[3], alv[3];
            #pragma unroll
            for (int e = 0; e < 3; ++e) {
                int h = 3 * hg + e;
                float mo = mL[h];
                float mn = fmaxf(mo, tm[e]);
                alv[e] = __expf(mo - mn);
                mnv[e] = mn;
                float ev = __expf(Lv[e] - mn);
                E[j * 14 + h] = ev;
                ss[e] = ev;
            }
            #pragma unroll
            for (int o = 32; o > 0; o >>= 1) {
                #pragma unroll
                for (int e = 0; e < 3; ++e) ss[e] += __shfl_xor(ss[e], o);
            }
            if (j == 0) {
                #pragma unroll
                for (int e = 0; e < 3; ++e) {
                    int h = 3 * hg + e;
                    mL[h] = mnv[e]; aL[h] = alv[e];
                    lL[h] = lL[h] * alv[e] + ss[e];
                }
            }
        }
        __syncthreads();   // E + aL ready

        // ---- Phase D: rescale + accumulate ----
        {   // r_pair: 256 threads (2 d-halves x 6 heads); E via aligned float2
            #pragma unroll
            for (int u = 0; u < 6; ++u) accp[u] *= aL[hb + u];
            #pragma unroll 4
            for (int jj = 0; jj < 64; ++jj) {
                float p = Pt[jj * 129 + dpr];
                const float2* ej = (const float2*)&E[jj * 14 + hb];  // hb even
                float2 e01 = ej[0], e23 = ej[1], e45 = ej[2];
                accp[0] = fmaf(e01.x, p, accp[0]);
                accp[1] = fmaf(e01.y, p, accp[1]);
                accp[2] = fmaf(e23.x, p, accp[2]);
                accp[3] = fmaf(e23.y, p, accp[3]);
                accp[4] = fmaf(e45.x, p, accp[4]);
                accp[5] = fmaf(e45.y, p, accp[5]);
            }
        }
        if (tid < 192) {   // r_scalar
            accs *= aL[hs];
            const float* vb = vs + (size_t)tile * 64 * 192 + tid;
            #pragma unroll 4
            for (int jj = 0; jj < 64; ++jj)
                accs = fmaf(E[jj * 14 + hs], vb[(size_t)jj * 192], accs);
        }
        if (tid < 144) {   // r_point (global frame)
            accq *= aL[hq];
            const float* vb = vpg + (size_t)tile * 64 * 144 + tid;
            #pragma unroll 4
            for (int jj = 0; jj < 64; ++jj)
                accq = fmaf(E[jj * 14 + hq], vb[(size_t)jj * 144], accq);
        }
        __syncthreads();   // protect Pt/E before next staging
    }

    // ---- epilogue ----
    if (tid < 12) invL[tid] = 1.0f / lL[tid];
    __syncthreads();

    #pragma unroll
    for (int u = 0; u < 6; ++u)
        results[ri + 384 + (size_t)(hb + u) * 128 + dpr] = accp[u] * invL[hb + u];

    if (tid < 192) results[ri + tid] = accs * invL[hs];

    if (tid < 144) {
        int pc = tid - hq * 12;
        int coord = pc - (pc / 3) * 3;
        rp_l[tid] = accq * invL[hq] - trans[i * 3 + coord];
    }
    __syncthreads();

    if (tid < 48) {
        int h = tid >> 2, d = tid & 3; int c0 = h * 12 + d * 3;
        float p0 = rp_l[c0], p1 = rp_l[c0 + 1], p2 = rp_l[c0 + 2];
        const float* R = rot + i * 9;
        float o0 = p0 * R[0] + p1 * R[3] + p2 * R[6];
        float o1 = p0 * R[1] + p1 * R[4] + p2 * R[7];
        float o2 = p0 * R[2] + p1 * R[5] + p2 * R[8];
        results[ri + 192 + c0 + 0] = o0;
        results[ri + 192 + c0 + 1] = o1;
        results[ri + 192 + c0 + 2] = o2;
        results[ri + 336 + h * 4 + d] = sqrtf(o0*o0 + o1*o1 + o2*o2 + 1e-8f);
    }
}

// -------------------- K3: out = results @ W_out + b_out --------------------
// grid 384 x 384 thr; 2 rows/block; 4-way k-split + LDS reduction.
__global__ __launch_bounds__(384) void k3_out(
    const float* __restrict__ results, const float* __restrict__ Wo, const float* __restrict__ bo,
    float* __restrict__ out)
{
    __shared__ float As[2 * 1920];
    __shared__ float red[3 * 96 * 9];

    const int t = threadIdx.x;
    const int r0 = blockIdx.x * 2;

    #pragma unroll
    for (int q = 0; q < 3; ++q) {
        int idx = t + 384 * q;
        if (idx < 960)
            ((float4*)As)[idx] = ((const float4*)(results + (size_t)r0 * 1920))[idx];
    }
    __syncthreads();

    const int cg = t % 96, kp = t / 96;
    float acc[2][4] = {};
    const float* wp = Wo + (size_t)(kp * 480) * 384 + cg * 4;
    const float* ap = As + kp * 480;
    #pragma unroll 4
    for (int k = 0; k < 480; ++k) {
        float4 w = *(const float4*)wp; wp += 384;
        #pragma unroll
        for (int r = 0; r < 2; ++r) {
            float a = ap[r * 1920 + k];   // broadcast
            acc[r][0] = fmaf(a, w.x, acc[r][0]);
            acc[r][1] = fmaf(a, w.y, acc[r][1]);
            acc[r][2] = fmaf(a, w.z, acc[r][2]);
            acc[r][3] = fmaf(a, w.w, acc[r][3]);
        }
    }
    if (kp > 0) {
        float* rp = &red[((kp - 1) * 96 + cg) * 9];
        #pragma unroll
        for (int r = 0; r < 2; ++r)
            #pragma unroll
            for (int u = 0; u < 4; ++u) rp[r * 4 + u] = acc[r][u];
    }
    __syncthreads();
    if (kp == 0) {
        float4 b = *(const float4*)(bo + cg * 4);
        #pragma unroll
        for (int r = 0; r < 2; ++r) {
            const float* r1 = &red[(0 * 96 + cg) * 9 + r * 4];
            const float* r2 = &red[(1 * 96 + cg) * 9 + r * 4];
            const float* r3 = &red[(2 * 96 + cg) * 9 + r * 4];
            float4 o;
            o.x = acc[r][0] + r1[0] + r2[0] + r3[0] + b.x;
            o.y = acc[r][1] + r1[1] + r2[1] + r3[1] + b.y;
            o.z = acc[r][2] + r1[2] + r2[2] + r3[2] + b.z;
            o.w = acc[r][3] + r1[3] + r2[3] + r3[3] + b.w;
            *(float4*)(out + (size_t)(r0 + r) * 384 + cg * 4) = o;
        }
    }
}

extern "C" void kernel_launch(void* const* d_in, const int* in_sizes, int n_in,
                              void* d_out, int out_size, void* d_ws, size_t ws_size,
                              hipStream_t stream) {
    const float* x        = (const float*)d_in[0];
    const float* pairwise = (const float*)d_in[1];
    const float* rot      = (const float*)d_in[2];
    const float* trans    = (const float*)d_in[3];
    // d_in[4] = mask: all-true in this problem; unused.
    const float* Wqs   = (const float*)d_in[5];
    const float* Wks   = (const float*)d_in[6];
    const float* Wvs   = (const float*)d_in[7];
    const float* Wqp   = (const float*)d_in[8];
    const float* Wkp   = (const float*)d_in[9];
    const float* Wvp   = (const float*)d_in[10];
    const float* Wp    = (const float*)d_in[11];
    const float* bp    = (const float*)d_in[12];
    const float* ptw   = (const float*)d_in[13];
    const float* Wo    = (const float*)d_in[14];
    const float* bo    = (const float*)d_in[15];
    float* out = (float*)d_out;

    float* ws = (float*)d_ws;
    float* qs      = ws;              // 768*192
    float* ksb     = qs   + 147456;
    float* vsb     = ksb  + 147456;
    float* qpg     = vsb  + 147456;   // 768*144
    float* kpg     = qpg  + 110592;
    float* vpg     = kpg  + 110592;
    float* results = vpg  + 110592;   // 768*1920

    hipLaunchKernelGGL(k1_proj, dim3(384), dim3(256), 0, stream,
                       x, rot, trans, Wqs, Wks, Wvs, Wqp, Wkp, Wvp,
                       qs, ksb, vsb, qpg, kpg, vpg);
    hipLaunchKernelGGL(k2_attn, dim3(768), dim3(256), 0, stream,
                       pairwise, rot, trans, Wp, bp, ptw,
                       qs, ksb, vsb, qpg, kpg, vpg, results);
    hipLaunchKernelGGL(k3_out, dim3(384), dim3(384), 0, stream,
                       results, Wo, bo, out);
}